// Round 3
// baseline (147.200 us; speedup 1.0000x reference)
//
#include <hip/hip_runtime.h>
#include <hip/hip_bf16.h>
#include <cstdint>
#include <cstddef>

// Problem constants (fixed by the reference setup)
#define BB 4
#define TT 2048
#define DM 1024
#define DH 64

typedef __attribute__((ext_vector_type(8))) short short8;   // 8 bf16 (4 VGPRs)
typedef __attribute__((ext_vector_type(4))) float floatx4;  // MFMA C/D

__device__ __forceinline__ unsigned short f2bf(float f) {
    union { float f; unsigned int u; } v; v.f = f;
    unsigned int u = v.u;
    u += 0x7fffu + ((u >> 16) & 1u);   // RNE; inputs are finite
    return (unsigned short)(u >> 16);
}

#define XQUADS (BB * TT * DM / 4)   // 2097152 float4-groups in x
#define WQUADS (DH * DM / 4)        // 16384 per weight matrix

// ---------------------------------------------------------------------------
// Kernel 0: fused fp32->bf16 conversion. x -> xb [8192][1024]; W_Q/W_K -> wb
// [128][1024] (rows 0..63 = W_Q, 64..127 = W_K). Pure streaming, ~50 MB.
// ---------------------------------------------------------------------------
__global__ __launch_bounds__(256) void conv_kernel(const float* __restrict__ x,
                                                   const float* __restrict__ wq,
                                                   const float* __restrict__ wk,
                                                   unsigned short* __restrict__ xb,
                                                   unsigned short* __restrict__ wb) {
    int i = blockIdx.x * 256 + threadIdx.x;      // one float4-group each
    const float* src;
    unsigned short* dst;
    if (i < XQUADS) {
        src = x + (size_t)i * 4;
        dst = xb + (size_t)i * 4;
    } else {
        int j = i - XQUADS;
        src = (j < WQUADS) ? (wq + (size_t)j * 4) : (wk + (size_t)(j - WQUADS) * 4);
        dst = wb + (size_t)j * 4;                // wk lands at wb + 65536 automatically
    }
    float4 v = *reinterpret_cast<const float4*>(src);
    ushort4 o;
    o.x = f2bf(v.x); o.y = f2bf(v.y); o.z = f2bf(v.z); o.w = f2bf(v.w);
    *reinterpret_cast<ushort4*>(dst) = o;
}

// ---------------------------------------------------------------------------
// Kernel 1: projection GEMM, all-bf16 inputs, no LDS. 512 blocks x 4 waves.
// Block owns a 16-row m-tile; wave w owns output cols [32w, 32w+32): waves 0-1
// produce Q (pre-scaled 1/32), waves 2-3 produce K (+ transposed copy kt).
// A-frags read b128 straight from xb (L1-shared across the 4 waves).
// ---------------------------------------------------------------------------
__global__ __launch_bounds__(256) void proj_kernel(const unsigned short* __restrict__ xb,
                                                   const unsigned short* __restrict__ wb,
                                                   unsigned short* __restrict__ qo,
                                                   unsigned short* __restrict__ ko,
                                                   unsigned short* __restrict__ kt) {
    const int tid  = threadIdx.x;
    const int wave = tid >> 6;
    const int lane = tid & 63;
    const int col  = lane & 15;
    const int quad = lane >> 4;
    const int m0   = blockIdx.x * 16;
    const int gc0  = wave * 32;                 // this wave's first output col (of 128)

    floatx4 acc0 = (floatx4){0.f, 0.f, 0.f, 0.f};
    floatx4 acc1 = (floatx4){0.f, 0.f, 0.f, 0.f};

    const unsigned short* xp  = xb + (size_t)(m0 + col) * DM + quad * 8;
    const unsigned short* wp0 = wb + (size_t)(gc0 + col) * DM + quad * 8;
    const unsigned short* wp1 = wp0 + (size_t)16 * DM;

#pragma unroll 4
    for (int k0 = 0; k0 < DM; k0 += 32) {
        short8 a  = *reinterpret_cast<const short8*>(xp  + k0);
        short8 b0 = *reinterpret_cast<const short8*>(wp0 + k0);
        short8 b1 = *reinterpret_cast<const short8*>(wp1 + k0);
        acc0 = __builtin_amdgcn_mfma_f32_16x16x32_bf16(a, b0, acc0, 0, 0, 0);
        acc1 = __builtin_amdgcn_mfma_f32_16x16x32_bf16(a, b1, acc1, 0, 0, 0);
    }

    // Epilogue: C/D layout col=lane&15, row=quad*4+reg.
#pragma unroll
    for (int nt = 0; nt < 2; ++nt) {
        const int g = gc0 + nt * 16 + col;       // global output col (0..127)
        const floatx4& acc = nt ? acc1 : acc0;
#pragma unroll
        for (int r = 0; r < 4; ++r) {
            const size_t row = (size_t)(m0 + quad * 4 + r);
            float v = acc[r];
            if (g < 64) {
                qo[row * DH + g] = f2bf(v * 0.03125f);    // exact 1/sqrt(1024)
            } else {
                unsigned short h = f2bf(v);
                const int n = g - 64;
                ko[row * DH + n] = h;
                const int b = (int)(row >> 11);
                const int s = (int)(row & 2047);
                kt[((size_t)(b * 64 + n)) * TT + s] = h;  // transposed copy
            }
        }
    }
}

// ---------------------------------------------------------------------------
// Kernel 2: flash phase 1 (split-K, 128-key chunks). Block = (b, qt, chunk);
// 2 waves, 32 q-rows, keys [128c, min(128c+128, q0+32)). QK^T B-frags from
// ko [s][d]; PV B-frags from kt [d][s]. P relayout via wave-private LDS.
// No __syncthreads. Writes unnormalized O + (m,l) per chunk.
// ---------------------------------------------------------------------------
__global__ __launch_bounds__(128) void flash1_kernel(const unsigned short* __restrict__ qb,
                                                     const unsigned short* __restrict__ kb,
                                                     const unsigned short* __restrict__ ktb,
                                                     float* __restrict__ Op,
                                                     float* __restrict__ ml) {
    const int c  = blockIdx.x & 15;         // key chunk (128 keys)
    const int qt = (blockIdx.x >> 4) & 63;  // q-tile (32 rows)
    const int b  = blockIdx.x >> 10;        // batch
    if (4 * c > qt) return;                 // chunk entirely beyond causal range

    __shared__ __align__(16) unsigned short Pl[2][16][32];  // per-wave P scratch

    const int tid  = threadIdx.x;
    const int wave = tid >> 6;
    const int lane = tid & 63;
    const int col  = lane & 15;
    const int quad = lane >> 4;

    const int q0    = qt * 32;
    const int qrow  = q0 + wave * 16;
    const int s_beg = c * 128;
    const int s_end = min(s_beg + 128, q0 + 32);

    const unsigned short* qp  = qb  + ((size_t)b * TT + qrow) * DH;
    const unsigned short* kp  = kb  + (size_t)b * TT * DH;
    const unsigned short* ktp = ktb + (size_t)b * 64 * TT;

    // Q A-frags (Q pre-scaled by 1/32)
    short8 qf0 = *reinterpret_cast<const short8*>(qp + (size_t)col * DH + quad * 8);
    short8 qf1 = *reinterpret_cast<const short8*>(qp + (size_t)col * DH + 32 + quad * 8);

    floatx4 o[4];
#pragma unroll
    for (int t = 0; t < 4; ++t) o[t] = (floatx4){0.f, 0.f, 0.f, 0.f};
    float mrow[4], lrow[4];
    int   myq[4];
#pragma unroll
    for (int r = 0; r < 4; ++r) {
        mrow[r] = -INFINITY; lrow[r] = 0.f;
        myq[r] = qrow + quad * 4 + r;
    }
    const float LOG2E = 1.44269504f;

    for (int s0 = s_beg; s0 < s_end; s0 += 32) {
        // ---- S = Q K^T (two 16-key subtiles), log2 domain + causal mask ----
        float sv[2][4];
        float mtile[4];
#pragma unroll
        for (int r = 0; r < 4; ++r) mtile[r] = -INFINITY;
#pragma unroll
        for (int st = 0; st < 2; ++st) {
            const unsigned short* kr = kp + (size_t)(s0 + st * 16 + col) * DH + quad * 8;
            short8 kf0 = *reinterpret_cast<const short8*>(kr);
            short8 kf1 = *reinterpret_cast<const short8*>(kr + 32);
            floatx4 z = (floatx4){0.f, 0.f, 0.f, 0.f};
            z = __builtin_amdgcn_mfma_f32_16x16x32_bf16(qf0, kf0, z, 0, 0, 0);
            z = __builtin_amdgcn_mfma_f32_16x16x32_bf16(qf1, kf1, z, 0, 0, 0);
            const int skey = s0 + st * 16 + col;
#pragma unroll
            for (int r = 0; r < 4; ++r) {
                float v = z[r] * LOG2E;
                v = (skey <= myq[r]) ? v : -INFINITY;
                sv[st][r] = v;
                mtile[r] = fmaxf(mtile[r], v);
            }
        }
#pragma unroll
        for (int m = 1; m < 16; m <<= 1)
#pragma unroll
            for (int r = 0; r < 4; ++r)
                mtile[r] = fmaxf(mtile[r], __shfl_xor(mtile[r], m, 64));

        // ---- online softmax update ----
        float alpha[4], rsum[4];
#pragma unroll
        for (int r = 0; r < 4; ++r) {
            float mnew = fmaxf(mrow[r], mtile[r]);
            alpha[r] = exp2f(mrow[r] - mnew);
            mrow[r] = mnew;
            float p0 = exp2f(sv[0][r] - mnew);
            float p1 = exp2f(sv[1][r] - mnew);
            sv[0][r] = p0; sv[1][r] = p1;
            rsum[r] = p0 + p1;
        }
#pragma unroll
        for (int m = 1; m < 16; m <<= 1)
#pragma unroll
            for (int r = 0; r < 4; ++r)
                rsum[r] += __shfl_xor(rsum[r], m, 64);
#pragma unroll
        for (int r = 0; r < 4; ++r) lrow[r] = lrow[r] * alpha[r] + rsum[r];
#pragma unroll
        for (int t = 0; t < 4; ++t)
#pragma unroll
            for (int r = 0; r < 4; ++r)
                o[t][r] *= alpha[r];

        // ---- P: C-layout regs -> A-layout via wave-private LDS (no barrier) ----
#pragma unroll
        for (int st = 0; st < 2; ++st)
#pragma unroll
            for (int r = 0; r < 4; ++r)
                Pl[wave][quad * 4 + r][st * 16 + col] = f2bf(sv[st][r]);
        short8 pf = *reinterpret_cast<const short8*>(&Pl[wave][col][quad * 8]);

        // ---- O += P V  (V == K), B-frags from global kt [d][s] ----
#pragma unroll
        for (int t = 0; t < 4; ++t) {
            short8 vf = *reinterpret_cast<const short8*>(
                ktp + (size_t)(t * 16 + col) * TT + s0 + quad * 8);
            o[t] = __builtin_amdgcn_mfma_f32_16x16x32_bf16(pf, vf, o[t], 0, 0, 0);
        }
    }

    // ---- store partial (unnormalized O, m, l) ----
    const int slot = (b * 64 + qt) * 16 + c;
    float* op = Op + (size_t)slot * 2048;           // [32][64]
#pragma unroll
    for (int t = 0; t < 4; ++t)
#pragma unroll
        for (int r = 0; r < 4; ++r)
            op[(size_t)(wave * 16 + quad * 4 + r) * DH + t * 16 + col] = o[t][r];
    if (col == 0) {
        float* mlp = ml + (size_t)slot * 64;        // [m[32], l[32]]
#pragma unroll
        for (int r = 0; r < 4; ++r) {
            mlp[wave * 16 + quad * 4 + r]      = mrow[r];
            mlp[32 + wave * 16 + quad * 4 + r] = lrow[r];
        }
    }
}

// ---------------------------------------------------------------------------
// Kernel 3: merge split-K partials. Block per (b, qt); thread owns 8 cols of
// one row. O = (sum_c w_c * O_c) / (sum_c w_c * l_c), w_c = exp2(m_c - M).
// ---------------------------------------------------------------------------
__global__ __launch_bounds__(256) void merge_kernel(const float* __restrict__ Op,
                                                    const float* __restrict__ ml,
                                                    float* __restrict__ out) {
    const int qt  = blockIdx.x & 63;
    const int b   = blockIdx.x >> 6;
    const int nch = (qt >> 2) + 1;    // 128-key chunks intersecting causal range
    const int t   = threadIdx.x;
    const int row = t >> 3;           // 0..31
    const int c8  = (t & 7) * 8;      // col group of 8
    const size_t base = (size_t)blockIdx.x * 16;

    float M = -INFINITY;
    for (int c = 0; c < nch; ++c)
        M = fmaxf(M, ml[(base + c) * 64 + row]);

    float L = 0.f;
    float a[8];
#pragma unroll
    for (int i = 0; i < 8; ++i) a[i] = 0.f;
    for (int c = 0; c < nch; ++c) {
        const float m_c = ml[(base + c) * 64 + row];
        const float l_c = ml[(base + c) * 64 + 32 + row];
        const float w = exp2f(m_c - M);
        L += l_c * w;
        const float* op = Op + (base + c) * 2048 + (size_t)row * 64 + c8;
        float4 v0 = *reinterpret_cast<const float4*>(op);
        float4 v1 = *reinterpret_cast<const float4*>(op + 4);
        a[0] += w * v0.x; a[1] += w * v0.y; a[2] += w * v0.z; a[3] += w * v0.w;
        a[4] += w * v1.x; a[5] += w * v1.y; a[6] += w * v1.z; a[7] += w * v1.w;
    }
    const float inv = 1.0f / L;
    float* o = out + ((size_t)b * TT + qt * 32 + row) * DH + c8;
    float4 r0 = {a[0] * inv, a[1] * inv, a[2] * inv, a[3] * inv};
    float4 r1 = {a[4] * inv, a[5] * inv, a[6] * inv, a[7] * inv};
    *reinterpret_cast<float4*>(o)     = r0;
    *reinterpret_cast<float4*>(o + 4) = r1;
}

// ---------------------------------------------------------------------------
extern "C" void kernel_launch(void* const* d_in, const int* in_sizes, int n_in,
                              void* d_out, int out_size, void* d_ws, size_t ws_size,
                              hipStream_t stream) {
    const float* x  = (const float*)d_in[0];
    const float* wq = (const float*)d_in[1];
    const float* wk = (const float*)d_in[2];
    // d_in[3] (W_V) is unused — faithful to the reference's source bug.

    unsigned short* xb = (unsigned short*)d_ws;          // [8192][1024] bf16 x
    unsigned short* qo = xb + (size_t)BB * TT * DM;      // [8192][64]  bf16 (pre-scaled)
    unsigned short* ko = qo + (size_t)BB * TT * DH;      // [8192][64]  bf16
    unsigned short* wb = ko + (size_t)BB * TT * DH;      // [128][1024] bf16
    unsigned short* kt = wb + (size_t)128 * DM;          // [4][64][2048] bf16 (K^T)
    float* Op = (float*)(kt + (size_t)BB * DH * TT);     // [4096][32][64] fp32 partials
    float* ml = Op + (size_t)4096 * 2048;                // [4096][64] fp32 (m,l)
    float* out = (float*)d_out;

    const int conv_blocks = (XQUADS + 2 * WQUADS + 255) / 256;   // 8320
    hipLaunchKernelGGL(conv_kernel,   dim3(conv_blocks),     dim3(256), 0, stream, x, wq, wk, xb, wb);
    hipLaunchKernelGGL(proj_kernel,   dim3((BB * TT) / 16),  dim3(256), 0, stream, xb, wb, qo, ko, kt);
    hipLaunchKernelGGL(flash1_kernel, dim3(BB * 64 * 16),    dim3(128), 0, stream, qo, ko, kt, Op, ml);
    hipLaunchKernelGGL(merge_kernel,  dim3(BB * 64),         dim3(256), 0, stream, Op, ml, out);
}